// Round 6
// baseline (151.928 us; speedup 1.0000x reference)
//
#include <hip/hip_runtime.h>

#define HH 32          // LSTM size
#define TT 20          // total steps (14 kernel + 3 down + 3 up)

typedef float v2f __attribute__((ext_vector_type(2)));

#define LOG2E  1.4426950408889634f
#define LN2    0.6931471805599453f

__device__ __forceinline__ float fsig(float x) {
    return __builtin_amdgcn_rcpf(1.0f + __builtin_amdgcn_exp2f(-x * LOG2E));
}
__device__ __forceinline__ float ftanh(float x) {
    return 1.0f - 2.0f * __builtin_amdgcn_rcpf(1.0f + __builtin_amdgcn_exp2f(x * (2.0f * LOG2E)));
}

// One block, ONE wave. Lane t owns all 4 gate rows of set q=t&31 (W_hh in 128
// VGPRs). G[e] = W_ih@emb[e]+bias precomputed into 15 float4 REGISTERS; the
// idx->gates edge is a cndmask tree (no memory on the chain). Embedding table
// base for the next input is the CURRENT step's table (reference semantics).
// Step loop fully unrolled: head select / class count / tree base constant-fold.
__global__ __launch_bounds__(64, 1) void controller_kernel(
    const float* __restrict__ w_ih,      // [128,32]
    const float* __restrict__ w_hh,      // [128,32]
    const float* __restrict__ b_ih,      // [128]
    const float* __restrict__ b_hh,      // [128]
    const float* __restrict__ g_emb,     // [1,32]
    const float* __restrict__ emb_kernel,// [8,32]
    const float* __restrict__ emb_down,  // [3,32]
    const float* __restrict__ emb_up,    // [3,32]
    const float* __restrict__ w_kernel,  // [8,32]
    const float* __restrict__ w_down,    // [3,32]
    const float* __restrict__ w_up,      // [3,32]
    const float* __restrict__ noise,     // [20,8]
    float* __restrict__ out)             // [22] = stats[2] ++ samples[20]
{
    const int t   = threadIdx.x;   // 0..63
    const int q   = t & 31;        // gate-set (lanes 32..63 duplicate — free)
    const int cls = t & 7;         // logit class this lane owns

    __shared__ __align__(16) float emb_s[15 * 32];   // 0..7 kern, 8..10 down, 11..13 up, 14 g_emb
    __shared__ __align__(16) float h_s[32];
    __shared__ __align__(16) float gum_s[TT * 8];

    // ---- stage embeddings + gumbel noise ----
    for (int i = t; i < 15 * 32; i += 64) {
        const int r = i >> 5, j = i & 31;
        float v;
        if (r < 8)       v = emb_kernel[i];
        else if (r < 11) v = emb_down[i - 8 * 32];
        else if (r < 14) v = emb_up[i - 11 * 32];
        else             v = g_emb[j];
        emb_s[i] = v;
    }
    for (int i = t; i < TT * 8; i += 64) {
        const float u = noise[i];
        gum_s[i] = -logf(-logf(u * (1.0f - 1e-6f) + 1e-7f));   // ocml: known-good
    }

    float bias[4];
#pragma unroll
    for (int g = 0; g < 4; ++g) bias[g] = b_ih[q + 32 * g] + b_hh[q + 32 * g];

    // ---- G precompute: Gall[e] = W_ih[rows q+32g] @ emb[e] + bias, in REGISTERS ----
    float4 Gall[15];
    {
        v2f wih[64];                                  // transient, dies before whh
#pragma unroll
        for (int g = 0; g < 4; ++g) {
            const float4* p = (const float4*)(w_ih + (q + 32 * g) * HH);
#pragma unroll
            for (int k8 = 0; k8 < 8; ++k8) {
                const float4 a = p[k8];
                wih[g * 16 + 2 * k8]     = (v2f){a.x, a.y};
                wih[g * 16 + 2 * k8 + 1] = (v2f){a.z, a.w};
            }
        }
        __syncthreads();   // emb_s / gum_s ready
#pragma unroll
        for (int e = 0; e < 15; ++e) {
            const float4* ep = (const float4*)(emb_s + e * 32);
            v2f g0 = {0.f,0.f}, g1 = {0.f,0.f}, g2 = {0.f,0.f}, g3 = {0.f,0.f};
#pragma unroll
            for (int k8 = 0; k8 < 8; ++k8) {
                const float4 a = ep[k8];
                const v2f e0 = {a.x, a.y}, e1 = {a.z, a.w};
                g0 += wih[2*k8]      * e0;  g0 += wih[2*k8+1]      * e1;
                g1 += wih[16+2*k8]   * e0;  g1 += wih[16+2*k8+1]   * e1;
                g2 += wih[32+2*k8]   * e0;  g2 += wih[32+2*k8+1]   * e1;
                g3 += wih[48+2*k8]   * e0;  g3 += wih[48+2*k8+1]   * e1;
            }
            Gall[e] = make_float4(bias[0] + g0.x + g0.y, bias[1] + g1.x + g1.y,
                                  bias[2] + g2.x + g2.y, bias[3] + g3.x + g3.y);
        }
    }
    __builtin_amdgcn_sched_barrier(0);   // keep whh/head loads out of the G phase

    // ---- W_hh resident (128 VGPRs) ----
    v2f whh[64];
#pragma unroll
    for (int g = 0; g < 4; ++g) {
        const float4* p = (const float4*)(w_hh + (q + 32 * g) * HH);
#pragma unroll
        for (int k8 = 0; k8 < 8; ++k8) {
            const float4 a = p[k8];
            whh[g * 16 + 2 * k8]     = (v2f){a.x, a.y};
            whh[g * 16 + 2 * k8 + 1] = (v2f){a.z, a.w};
        }
    }
    // ---- heads for my class (hd/hu only valid for cls<3; others masked later) ----
    v2f hk[16], hd[16], hu[16];
#pragma unroll
    for (int k8 = 0; k8 < 8; ++k8) {
        const float4 a = ((const float4*)(w_kernel + cls * 32))[k8];
        hk[2*k8] = (v2f){a.x, a.y}; hk[2*k8+1] = (v2f){a.z, a.w};
        float4 b = make_float4(0.f,0.f,0.f,0.f), c = make_float4(0.f,0.f,0.f,0.f);
        if (cls < 3) {
            b = ((const float4*)(w_down + cls * 32))[k8];
            c = ((const float4*)(w_up + cls * 32))[k8];
        }
        hd[2*k8] = (v2f){b.x, b.y}; hd[2*k8+1] = (v2f){b.z, b.w};
        hu[2*k8] = (v2f){c.x, c.y}; hu[2*k8+1] = (v2f){c.z, c.w};
    }

    v2f hreg[16];
#pragma unroll
    for (int k = 0; k < 16; ++k) hreg[k] = (v2f){0.f, 0.f};
    float  c_reg = 0.0f;
    float4 G4 = Gall[14];                // first x = g_emb
    float  lp_sum = 0.0f, ent_sum = 0.0f;

#pragma unroll
    for (int step = 0; step < TT; ++step) {
        // ---- A: gates = G4 + W_hh @ h (4 rows lane-local) ----
        v2f ai0={0.f,0.f}, af0={0.f,0.f}, ag0={0.f,0.f}, ao0={0.f,0.f};
        v2f ai1={0.f,0.f}, af1={0.f,0.f}, ag1={0.f,0.f}, ao1={0.f,0.f};
#pragma unroll
        for (int k = 0; k < 16; k += 2) {
            ai0 += whh[k]      * hreg[k];  ai1 += whh[k+1]      * hreg[k+1];
            af0 += whh[16+k]   * hreg[k];  af1 += whh[16+k+1]   * hreg[k+1];
            ag0 += whh[32+k]   * hreg[k];  ag1 += whh[32+k+1]   * hreg[k+1];
            ao0 += whh[48+k]   * hreg[k];  ao1 += whh[48+k+1]   * hreg[k+1];
        }
        const float ai = G4.x + ((ai0.x+ai0.y) + (ai1.x+ai1.y));
        const float af = G4.y + ((af0.x+af0.y) + (af1.x+af1.y));
        const float ag = G4.z + ((ag0.x+ag0.y) + (ag1.x+ag1.y));
        const float ao = G4.w + ((ao0.x+ao0.y) + (ao1.x+ao1.y));

        // ---- B: cell (all lanes duplicate; same value -> benign 2-way LDS write) ----
        const float ig = fsig(ai), fg = fsig(af), gg = ftanh(ag), og = fsig(ao);
        c_reg = fg * c_reg + ig * gg;
        const float hn = og * ftanh(c_reg);
        h_s[q] = hn;
        __syncthreads();
#pragma unroll
        for (int k8 = 0; k8 < 8; ++k8) {               // broadcast reads: conflict-free
            const float4 hv = ((const float4*)h_s)[k8];
            hreg[2*k8] = (v2f){hv.x, hv.y}; hreg[2*k8+1] = (v2f){hv.z, hv.w};
        }

        // ---- C: full 32-dot logit for class cls (constant head after unroll) ----
        const int n = (step < 14) ? 8 : 3;
        v2f s0 = {0.f,0.f}, s1 = {0.f,0.f};
        if (step < 14) {
#pragma unroll
            for (int k = 0; k < 16; k += 2) { s0 += hk[k]*hreg[k]; s1 += hk[k+1]*hreg[k+1]; }
        } else if (step < 17) {
#pragma unroll
            for (int k = 0; k < 16; k += 2) { s0 += hd[k]*hreg[k]; s1 += hd[k+1]*hreg[k+1]; }
        } else {
#pragma unroll
            for (int k = 0; k < 16; k += 2) { s0 += hu[k]*hreg[k]; s1 += hu[k+1]*hreg[k+1]; }
        }
        float l = (s0.x + s0.y) + (s1.x + s1.y);
        l = (cls < n) ? l : -1e9f;

        // ---- D: gather 8 logits; lane-local stats + pairwise argmax tree ----
        float lv[8];
#pragma unroll
        for (int k = 0; k < 8; ++k) lv[k] = __shfl(l, k);

        float S = 0.0f, Tm = 0.0f;
#pragma unroll
        for (int k = 0; k < 8; ++k) {
            const float e = __builtin_amdgcn_exp2f(lv[k] * LOG2E);  // masked -> 0
            S += e; Tm += e * lv[k];
        }
        const float4 gA = ((const float4*)(gum_s + step * 8))[0];
        const float4 gB = ((const float4*)(gum_s + step * 8))[1];
        const float v0 = lv[0]+gA.x, v1 = lv[1]+gA.y, v2 = lv[2]+gA.z, v3 = lv[3]+gA.w;
        const float v4 = lv[4]+gB.x, v5 = lv[5]+gB.y, v6 = lv[6]+gB.z, v7 = lv[7]+gB.w;
        // strict > at every level keeps the FIRST max index (jnp.argmax rule)
        const bool ta = v1 > v0;  const float va = ta?v1:v0;  int ia = ta?1:0;  const float la = ta?lv[1]:lv[0];
        const bool tb = v3 > v2;  const float vb = tb?v3:v2;  int ib = tb?3:2;  const float lb = tb?lv[3]:lv[2];
        const bool tc = v5 > v4;  const float vc = tc?v5:v4;  int ic = tc?5:4;  const float lc = tc?lv[5]:lv[4];
        const bool td = v7 > v6;  const float vd = td?v7:v6;  int id_= td?7:6;  const float ld = td?lv[7]:lv[6];
        const bool tab = vb > va; const float vab = tab?vb:va; const int iab = tab?ib:ia; const float lab = tab?lb:la;
        const bool tcd = vd > vc; const float vcd = tcd?vd:vc; const int icd = tcd?id_:ic; const float lcd = tcd?ld:lc;
        const bool tf  = vcd > vab;
        const int   idx = tf ? icd : iab;
        const float bl  = tf ? lcd : lab;

        const float lse = __builtin_amdgcn_logf(S) * LN2;
        lp_sum  += bl - lse;
        ent_sum += lse - Tm * __builtin_amdgcn_rcpf(S);
        if (t == 0) out[2 + step] = (float)idx;

        // ---- E: next G4 via cndmask tree; table base = CURRENT step (ref semantics) ----
        if (step < TT - 1) {
            if (step < 14) {                      // rows 0..7
                const float4 s01 = (idx & 1) ? Gall[1] : Gall[0];
                const float4 s23 = (idx & 1) ? Gall[3] : Gall[2];
                const float4 s45 = (idx & 1) ? Gall[5] : Gall[4];
                const float4 s67 = (idx & 1) ? Gall[7] : Gall[6];
                const float4 sA  = (idx & 2) ? s23 : s01;
                const float4 sB  = (idx & 2) ? s67 : s45;
                G4 = (idx & 4) ? sB : sA;
            } else if (step < 17) {               // rows 8..10 (idx<3 guaranteed)
                const float4 a = (idx == 1) ? Gall[9] : Gall[8];
                G4 = (idx == 2) ? Gall[10] : a;
            } else {                              // rows 11..13
                const float4 a = (idx == 1) ? Gall[12] : Gall[11];
                G4 = (idx == 2) ? Gall[13] : a;
            }
        }
    }

    if (t == 0) {
        out[0] = lp_sum;
        out[1] = ent_sum;
    }
}

extern "C" void kernel_launch(void* const* d_in, const int* in_sizes, int n_in,
                              void* d_out, int out_size, void* d_ws, size_t ws_size,
                              hipStream_t stream) {
    (void)in_sizes; (void)n_in; (void)out_size; (void)d_ws; (void)ws_size;
    const float* w_ih       = (const float*)d_in[0];
    const float* w_hh       = (const float*)d_in[1];
    const float* b_ih       = (const float*)d_in[2];
    const float* b_hh       = (const float*)d_in[3];
    const float* g_emb      = (const float*)d_in[4];
    const float* emb_kernel = (const float*)d_in[5];
    const float* emb_down   = (const float*)d_in[6];
    const float* emb_up     = (const float*)d_in[7];
    const float* w_kernel   = (const float*)d_in[8];
    const float* w_down     = (const float*)d_in[9];
    const float* w_up       = (const float*)d_in[10];
    const float* noise      = (const float*)d_in[11];
    float* out = (float*)d_out;

    hipLaunchKernelGGL(controller_kernel, dim3(1), dim3(64), 0, stream,
                       w_ih, w_hh, b_ih, b_hh, g_emb, emb_kernel, emb_down,
                       emb_up, w_kernel, w_down, w_up, noise, out);
}

// Round 7
// 94.561 us; speedup vs baseline: 1.6067x; 1.6067x over previous
//
#include <hip/hip_runtime.h>

#define HH 32          // LSTM size
#define TT 20          // total steps (14 kernel + 3 down + 3 up)

typedef float v2f __attribute__((ext_vector_type(2)));

#define LOG2E  1.4426950408889634f
#define LN2    0.6931471805599453f

__device__ __forceinline__ float fsig(float x) {
    return __builtin_amdgcn_rcpf(1.0f + __builtin_amdgcn_exp2f(-x * LOG2E));
}
__device__ __forceinline__ float ftanh(float x) {
    return 1.0f - 2.0f * __builtin_amdgcn_rcpf(1.0f + __builtin_amdgcn_exp2f(x * (2.0f * LOG2E)));
}

// One block, ONE wave. Budget-aware (256 arch-VGPR cap — R6 spilled at 316):
// resident = whh 4 gate rows (128 VGPRs) + hreg (32) + hk kernel head (32).
// G[e]=W_ih@emb[e]+bias precomputed in LDS (halves split the 15 embeddings);
// idx->gates edge = one ds_read_b128 overlapped with the next FMA stream.
// i,f,g,o lane-local (no gate shuffles). Sampling: 8 shfl gathers + local
// pairwise strict-> argmax tree. Tail steps (6 of 20) use LDS head partials.
// Next-input table base = CURRENT step (reference scan semantics).
__global__ __launch_bounds__(64, 1) void controller_kernel(
    const float* __restrict__ w_ih,      // [128,32]
    const float* __restrict__ w_hh,      // [128,32]
    const float* __restrict__ b_ih,      // [128]
    const float* __restrict__ b_hh,      // [128]
    const float* __restrict__ g_emb,     // [1,32]
    const float* __restrict__ emb_kernel,// [8,32]
    const float* __restrict__ emb_down,  // [3,32]
    const float* __restrict__ emb_up,    // [3,32]
    const float* __restrict__ w_kernel,  // [8,32]
    const float* __restrict__ w_down,    // [3,32]
    const float* __restrict__ w_up,      // [3,32]
    const float* __restrict__ noise,     // [20,8]
    float* __restrict__ out)             // [22] = stats[2] ++ samples[20]
{
    const int t   = threadIdx.x;   // 0..63
    const int q   = t & 31;        // gate-set (lanes 32..63 duplicate the cell)
    const int cls = t & 7;         // logit class this lane owns

    __shared__ __align__(16) float emb_s[15 * 32];    // 0..7 kern, 8..10 down, 11..13 up, 14 g_emb
    __shared__ __align__(16) float Gv[15 * 32 * 4];   // [e][q][4] = (i,f,g,o) precomp
    __shared__ __align__(16) float h_s[32];
    __shared__ __align__(16) float gum_s[TT * 8];
    __shared__ __align__(16) float head_pre[2 * 64 * 4]; // tail heads (down,up) per-lane float4

    // ---- stage embeddings, gumbel noise, tail-head prearrange ----
    for (int i = t; i < 15 * 32; i += 64) {
        const int r = i >> 5, j = i & 31;
        float v;
        if (r < 8)       v = emb_kernel[i];
        else if (r < 11) v = emb_down[i - 8 * 32];
        else if (r < 14) v = emb_up[i - 11 * 32];
        else             v = g_emb[j];
        emb_s[i] = v;
    }
    for (int i = t; i < TT * 8; i += 64) {
        const float u = noise[i];
        gum_s[i] = -logf(-logf(u * (1.0f - 1e-6f) + 1e-7f));   // off critical path
    }
#pragma unroll
    for (int bi = 0; bi < 2; ++bi) {                 // 0=down, 1=up
        float4 v = make_float4(0.f, 0.f, 0.f, 0.f);
        if (cls < 3) {
            const float* W = (bi == 0) ? w_down : w_up;
            v = *(const float4*)(W + cls * 32 + (t >> 3) * 4);
        }
        *(float4*)(head_pre + (bi * 64 + t) * 4) = v;
    }

    float bias[4];
#pragma unroll
    for (int g = 0; g < 4; ++g) bias[g] = b_ih[q + 32 * g] + b_hh[q + 32 * g];

    // ---- G precompute into LDS; half-waves split the 15 embeddings ----
    {
        v2f wih[64];                                  // transient; dies before whh loads
#pragma unroll
        for (int g = 0; g < 4; ++g) {
            const float4* p = (const float4*)(w_ih + (q + 32 * g) * HH);
#pragma unroll
            for (int k8 = 0; k8 < 8; ++k8) {
                const float4 a = p[k8];
                wih[g * 16 + 2 * k8]     = (v2f){a.x, a.y};
                wih[g * 16 + 2 * k8 + 1] = (v2f){a.z, a.w};
            }
        }
        __syncthreads();   // emb_s ready
        const int e0 = (t < 32) ? 0 : 8;
        const int e1 = (t < 32) ? 8 : 15;
        for (int e = e0; e < e1; ++e) {
            const float4* ep = (const float4*)(emb_s + e * 32);
            v2f g0 = {0.f,0.f}, g1 = {0.f,0.f}, g2 = {0.f,0.f}, g3 = {0.f,0.f};
#pragma unroll
            for (int k8 = 0; k8 < 8; ++k8) {
                const float4 a = ep[k8];
                const v2f x0 = {a.x, a.y}, x1 = {a.z, a.w};
                g0 += wih[2*k8]    * x0;  g0 += wih[2*k8+1]    * x1;
                g1 += wih[16+2*k8] * x0;  g1 += wih[16+2*k8+1] * x1;
                g2 += wih[32+2*k8] * x0;  g2 += wih[32+2*k8+1] * x1;
                g3 += wih[48+2*k8] * x0;  g3 += wih[48+2*k8+1] * x1;
            }
            *(float4*)(Gv + (e * 32 + q) * 4) =
                make_float4(bias[0] + g0.x + g0.y, bias[1] + g1.x + g1.y,
                            bias[2] + g2.x + g2.y, bias[3] + g3.x + g3.y);
        }
    }
    __syncthreads();       // Gv ready
    __builtin_amdgcn_sched_barrier(0);   // keep whh/hk loads out of the G phase

    // ---- resident weights: whh (128 VGPRs) + kernel head hk (32 VGPRs) ----
    v2f whh[64];
#pragma unroll
    for (int g = 0; g < 4; ++g) {
        const float4* p = (const float4*)(w_hh + (q + 32 * g) * HH);
#pragma unroll
        for (int k8 = 0; k8 < 8; ++k8) {
            const float4 a = p[k8];
            whh[g * 16 + 2 * k8]     = (v2f){a.x, a.y};
            whh[g * 16 + 2 * k8 + 1] = (v2f){a.z, a.w};
        }
    }
    v2f hk[16];
#pragma unroll
    for (int k8 = 0; k8 < 8; ++k8) {
        const float4 a = ((const float4*)(w_kernel + cls * 32))[k8];
        hk[2*k8] = (v2f){a.x, a.y}; hk[2*k8+1] = (v2f){a.z, a.w};
    }

    v2f hreg[16];
#pragma unroll
    for (int k = 0; k < 16; ++k) hreg[k] = (v2f){0.f, 0.f};
    float  c_reg = 0.0f;
    float4 G4 = *(const float4*)(Gv + (14 * 32 + q) * 4);   // first x = g_emb
    float  lp_sum = 0.0f, ent_sum = 0.0f;

    for (int step = 0; step < TT; ++step) {
        // ---- A: gates = G4 + W_hh @ h (4 rows lane-local) ----
        v2f ai = {0.f,0.f}, af = {0.f,0.f}, ag = {0.f,0.f}, ao = {0.f,0.f};
#pragma unroll
        for (int k = 0; k < 16; ++k) {
            ai += whh[k]      * hreg[k];
            af += whh[16 + k] * hreg[k];
            ag += whh[32 + k] * hreg[k];
            ao += whh[48 + k] * hreg[k];
        }
        const float gi_ = G4.x + ai.x + ai.y;
        const float gf_ = G4.y + af.x + af.y;
        const float gg_ = G4.z + ag.x + ag.y;
        const float go_ = G4.w + ao.x + ao.y;

        // ---- B: cell (both halves duplicate; lanes 0..31 write h) ----
        const float ig = fsig(gi_), fg = fsig(gf_), gv = ftanh(gg_), og = fsig(go_);
        c_reg = fg * c_reg + ig * gv;
        const float hn = og * ftanh(c_reg);
        if (t < 32) h_s[t] = hn;
        __syncthreads();

        // ---- broadcast h into regs (feeds logit dot and next step's gates) ----
#pragma unroll
        for (int k8 = 0; k8 < 8; ++k8) {
            const float4 hv = ((const float4*)h_s)[k8];
            hreg[2*k8] = (v2f){hv.x, hv.y}; hreg[2*k8+1] = (v2f){hv.z, hv.w};
        }

        // ---- C: logit for class cls ----
        float l;
        if (step < 14) {                       // kernel head: resident, full 32-dot
            v2f s0 = {0.f,0.f}, s1 = {0.f,0.f};
#pragma unroll
            for (int k = 0; k < 16; k += 2) { s0 += hk[k]*hreg[k]; s1 += hk[k+1]*hreg[k+1]; }
            l = (s0.x + s0.y) + (s1.x + s1.y);  // n=8: no masking
        } else {                               // down/up: LDS partial + 3 xor shuffles
            const int bi = (step < 17) ? 0 : 1;
            const float4 hp = *(const float4*)(head_pre + (bi * 64 + t) * 4);
            const float4 hv = ((const float4*)h_s)[t >> 3];
            float p = hp.x*hv.x + hp.y*hv.y + hp.z*hv.z + hp.w*hv.w;
            p += __shfl_xor(p, 8);
            p += __shfl_xor(p, 16);
            p += __shfl_xor(p, 32);
            l = (cls < 3) ? p : -1e9f;
        }

        // ---- D: gather 8 logits; lane-local stats + pairwise argmax tree ----
        float lv[8];
#pragma unroll
        for (int k = 0; k < 8; ++k) lv[k] = __shfl(l, k);

        float S = 0.0f, Tm = 0.0f;
#pragma unroll
        for (int k = 0; k < 8; ++k) {
            const float e = __builtin_amdgcn_exp2f(lv[k] * LOG2E);  // masked -> 0
            S += e; Tm += e * lv[k];
        }
        const float4 gA = ((const float4*)(gum_s + step * 8))[0];
        const float4 gB = ((const float4*)(gum_s + step * 8))[1];
        const float v0 = lv[0]+gA.x, v1 = lv[1]+gA.y, v2 = lv[2]+gA.z, v3 = lv[3]+gA.w;
        const float v4 = lv[4]+gB.x, v5 = lv[5]+gB.y, v6 = lv[6]+gB.z, v7 = lv[7]+gB.w;
        // strict > at every level keeps the FIRST max index (jnp.argmax rule)
        const bool ta = v1 > v0;  const float va = ta?v1:v0;  const int ia = ta?1:0;  const float la = ta?lv[1]:lv[0];
        const bool tb = v3 > v2;  const float vb = tb?v3:v2;  const int ib = tb?3:2;  const float lb = tb?lv[3]:lv[2];
        const bool tc = v5 > v4;  const float vc = tc?v5:v4;  const int ic = tc?5:4;  const float lc = tc?lv[5]:lv[4];
        const bool td = v7 > v6;  const float vd = td?v7:v6;  const int id_= td?7:6;  const float ld = td?lv[7]:lv[6];
        const bool tab = vb > va; const float vab = tab?vb:va; const int iab = tab?ib:ia; const float lab = tab?lb:la;
        const bool tcd = vd > vc; const float vcd = tcd?vd:vc; const int icd = tcd?id_:ic; const float lcd = tcd?ld:lc;
        const bool tf  = vcd > vab;
        const int   idx = tf ? icd : iab;
        const float bl  = tf ? lcd : lab;

        const float lse = __builtin_amdgcn_logf(S) * LN2;
        lp_sum  += bl - lse;
        ent_sum += lse - Tm * __builtin_amdgcn_rcpf(S);
        if (t == 0) out[2 + step] = (float)idx;

        // ---- E: next G4; table base = CURRENT step (reference semantics) ----
        const int base = (step < 14) ? 0 : ((step < 17) ? 8 : 11);
        G4 = *(const float4*)(Gv + ((base + idx) * 32 + q) * 4);
    }

    if (t == 0) {
        out[0] = lp_sum;
        out[1] = ent_sum;
    }
}

extern "C" void kernel_launch(void* const* d_in, const int* in_sizes, int n_in,
                              void* d_out, int out_size, void* d_ws, size_t ws_size,
                              hipStream_t stream) {
    (void)in_sizes; (void)n_in; (void)out_size; (void)d_ws; (void)ws_size;
    const float* w_ih       = (const float*)d_in[0];
    const float* w_hh       = (const float*)d_in[1];
    const float* b_ih       = (const float*)d_in[2];
    const float* b_hh       = (const float*)d_in[3];
    const float* g_emb      = (const float*)d_in[4];
    const float* emb_kernel = (const float*)d_in[5];
    const float* emb_down   = (const float*)d_in[6];
    const float* emb_up     = (const float*)d_in[7];
    const float* w_kernel   = (const float*)d_in[8];
    const float* w_down     = (const float*)d_in[9];
    const float* w_up       = (const float*)d_in[10];
    const float* noise      = (const float*)d_in[11];
    float* out = (float*)d_out;

    hipLaunchKernelGGL(controller_kernel, dim3(1), dim3(64), 0, stream,
                       w_ih, w_hh, b_ih, b_hh, g_emb, emb_kernel, emb_down,
                       emb_up, w_kernel, w_down, w_up, noise, out);
}